// Round 5
// baseline (1800.427 us; speedup 1.0000x reference)
//
#include <hip/hip_runtime.h>
#include <hip/hip_bf16.h>
#include <math.h>

// Problem constants (match reference)
#define N_NODES 100000
#define N_EDGES 3200000
#define HID 128
#define LAYERS 8
#define ALPHA 0.1f
#define THETA 0.5f

#define SH 8                                  // src chunks (for indptr8 sub-segments)
#define CHDIV 12500                           // nodes per src chunk
#define NODES8 (N_NODES * SH)                 // 800000 histogram entries
#define SCAN_TILE 4096                        // elems per scan block (256 thr x 16)
#define NB_SCAN ((NODES8 + SCAN_TILE - 1) / SCAN_TILE)   // 196 (<= 256)

#define NBKT ((N_NODES + 63) / 64)            // 1563 dst buckets (64 nodes each)
#define NBKT8 (NBKT * 8)                      // 12504 bucket x shard streams
#define BPT 49                                // bscan elems/thread (256*49=12544)

typedef unsigned int uint;
typedef unsigned short ushort;
typedef __attribute__((ext_vector_type(8))) short short8;   // 8 bf16 (4 VGPRs)
typedef __attribute__((ext_vector_type(4))) float f32x4;    // MFMA acc

// bf16 helpers: node features stored as packed bf16 pairs (uint = 2 cols)
__device__ inline float bf_lo(uint p) { return __uint_as_float(p << 16); }
__device__ inline float bf_hi(uint p) { return __uint_as_float(p & 0xffff0000u); }
__device__ inline uint bf_pack(float x, float y) {
    uint ux = __float_as_uint(x), uy = __float_as_uint(y);
    uint rx = (ux + 0x7fffu + ((ux >> 16) & 1u)) >> 16;
    uint ry = (uy + 0x7fffu + ((uy >> 16) & 1u)) >> 16;
    return rx | (ry << 16);
}
__device__ inline ushort bfr(float x) {
    uint u = __float_as_uint(x);
    return (ushort)((u + 0x7fffu + ((u >> 16) & 1u)) >> 16);
}
__device__ inline float bff(ushort s) { return __uint_as_float(((uint)s) << 16); }

// ---------------------------------------------------------------------------
// Histograms: cnt8[(dst,srcchunk)] for indptr8/dinv; bktcnt8[(bucket,shard)]
// for the pass-1 append streams.
// ---------------------------------------------------------------------------
__global__ __launch_bounds__(256) void k_count(const int* __restrict__ rowi,
                                               const int* __restrict__ coli,
                                               int* __restrict__ cnt8,
                                               int* __restrict__ bktcnt8) {
    int e = blockIdx.x * 256 + threadIdx.x;
    if (e >= N_EDGES) return;
    int r = rowi[e];
    int c = coli[e];
    int chunk = r / CHDIV;
    atomicAdd(&cnt8[c * SH + chunk], 1);
    atomicAdd(&bktcnt8[(c >> 6) * 8 + (blockIdx.x & 7)], 1);
}

__global__ __launch_bounds__(256) void k_dinv(const int* __restrict__ cnt8,
                                              float* __restrict__ dinv) {
    int n = blockIdx.x * 256 + threadIdx.x;
    if (n >= N_NODES) return;
    int4 a = *(const int4*)(cnt8 + n * SH);
    int4 b = *(const int4*)(cnt8 + n * SH + 4);
    int deg = a.x + a.y + a.z + a.w + b.x + b.y + b.z + b.w;
    dinv[n] = rsqrtf((float)(deg + 1));  // +1 self loop
}

// Exclusive scan over NODES8 entries, 3 kernels, 16 elems/thread.
__global__ __launch_bounds__(256) void k_scan1(const int* __restrict__ cnt8,
                                               int* __restrict__ indptr8,
                                               int* __restrict__ bsum) {
    __shared__ int lds[256];
    int t = threadIdx.x;
    int base = blockIdx.x * SCAN_TILE + t * 16;
    int v[16];
    int s = 0;
#pragma unroll
    for (int j = 0; j < 16; ++j) {
        v[j] = (base + j < NODES8) ? cnt8[base + j] : 0;
        s += v[j];
    }
    lds[t] = s;
    __syncthreads();
    for (int off = 1; off < 256; off <<= 1) {
        int u = (t >= off) ? lds[t - off] : 0;
        __syncthreads();
        lds[t] += u;
        __syncthreads();
    }
    int run = lds[t] - s;
#pragma unroll
    for (int j = 0; j < 16; ++j) {
        if (base + j < NODES8) indptr8[base + j] = run;
        run += v[j];
    }
    if (t == 255) bsum[blockIdx.x] = lds[255];
}

__global__ __launch_bounds__(256) void k_scan2(const int* __restrict__ bsum,
                                               int* __restrict__ boff) {
    __shared__ int lds[256];
    int t = threadIdx.x;
    int v = (t < NB_SCAN) ? bsum[t] : 0;
    lds[t] = v;
    __syncthreads();
    for (int off = 1; off < 256; off <<= 1) {
        int u = (t >= off) ? lds[t - off] : 0;
        __syncthreads();
        lds[t] += u;
        __syncthreads();
    }
    boff[t] = lds[t] - v;
}

__global__ __launch_bounds__(256) void k_scan3(int* __restrict__ indptr8,
                                               const int* __restrict__ boff) {
    int base = blockIdx.x * SCAN_TILE + threadIdx.x * 16;
    int add = boff[blockIdx.x];
#pragma unroll
    for (int j = 0; j < 16; ++j) {
        if (base + j < NODES8) indptr8[base + j] += add;
    }
    if (blockIdx.x == 0 && threadIdx.x == 0) indptr8[NODES8] = N_EDGES;
}

// Single-block exclusive scan over NBKT8 streams -> start cursors + ranges.
__global__ __launch_bounds__(256) void k_bscan(const int* __restrict__ bktcnt8,
                                               int* __restrict__ bktcur,
                                               int* __restrict__ bktptr8) {
    __shared__ int lds[256];
    int t = threadIdx.x;
    int base = t * BPT;
    int v[BPT];
    int s = 0;
#pragma unroll
    for (int j = 0; j < BPT; ++j) {
        v[j] = (base + j < NBKT8) ? bktcnt8[base + j] : 0;
        s += v[j];
    }
    lds[t] = s;
    __syncthreads();
    for (int off = 1; off < 256; off <<= 1) {
        int u = (t >= off) ? lds[t - off] : 0;
        __syncthreads();
        lds[t] += u;
        __syncthreads();
    }
    int run = lds[t] - s;
#pragma unroll
    for (int j = 0; j < BPT; ++j) {
        if (base + j < NBKT8) { bktcur[base + j] = run; bktptr8[base + j] = run; }
        run += v[j];
    }
    if (t == 255) bktptr8[NBKT8] = N_EDGES;
}

// ---------------------------------------------------------------------------
// Pass 1: append records to (bucket, shard) streams. Active write front =
// 12.5k lines (~800 KB) -> lines fill in L2 before eviction.
// rec.x = src(17b) | coff(6b)<<17 | chunk(3b)<<23 ; rec.y = nrm bits
// ---------------------------------------------------------------------------
__global__ __launch_bounds__(256) void k_bin(const int* __restrict__ rowi,
                                             const int* __restrict__ coli,
                                             const float* __restrict__ dinv,
                                             int* __restrict__ bktcur,
                                             int2* __restrict__ binned) {
    int e = blockIdx.x * 256 + threadIdx.x;
    if (e >= N_EDGES) return;
    int r = rowi[e];
    int c = coli[e];
    int chunk = r / CHDIV;
    int stream = (c >> 6) * 8 + (blockIdx.x & 7);
    int p = atomicAdd(&bktcur[stream], 1);
    uint key = (uint)r | ((uint)(c & 63) << 17) | ((uint)chunk << 23);
    binned[p] = make_int2((int)key, __float_as_int(dinv[r] * dinv[c]));
}

// ---------------------------------------------------------------------------
// Pass 2: one block per bucket; scatter records into the bucket's ~16 KB
// contiguous CSR window using LDS cursors (64 nodes x 8 chunks).
// ---------------------------------------------------------------------------
__global__ __launch_bounds__(256) void k_scatter(const int2* __restrict__ binned,
                                                 const int* __restrict__ bktptr8,
                                                 const int* __restrict__ indptr8,
                                                 int2* __restrict__ csr) {
    __shared__ int cur[512];
    int b = blockIdx.x;
    int t = threadIdx.x;
    int nb = b * 64;
#pragma unroll
    for (int i = 0; i < 2; ++i) {
        int idx = t + 256 * i;           // 0..511 = nodeLocal*8 + chunk
        int node = nb + (idx >> 3);
        cur[idx] = (node < N_NODES) ? indptr8[node * SH + (idx & 7)] : 0;
    }
    __syncthreads();
    int beg = bktptr8[b * 8];
    int end = bktptr8[b * 8 + 8];
    for (int i = beg + t; i < end; i += 256) {
        int2 rec = binned[i];
        uint key = (uint)rec.x;
        int src = key & 0x1FFFF;
        int coff = (key >> 17) & 63;
        int chunk = (key >> 23) & 7;
        int pos = atomicAdd(&cur[coff * 8 + chunk], 1);
        csr[pos] = make_int2(src, rec.y);
    }
}

// ---------------------------------------------------------------------------
// W_gcn prep: bf16 + transpose -> Wt[l][c][k]  (runs once per call, 8 blocks)
// ---------------------------------------------------------------------------
__global__ __launch_bounds__(256) void k_wprep(const float* __restrict__ Wg,
                                               ushort* __restrict__ Wt) {
    int l = blockIdx.x;
    const float* W = Wg + (size_t)l * HID * HID;
    ushort* T = Wt + (size_t)l * HID * HID;
    int t = threadIdx.x;
#pragma unroll
    for (int i = 0; i < 16; ++i) {
        int idx = t + 256 * i;          // float4 id, 0..4095
        int k = idx >> 5;               // 0..127
        int c4 = idx & 31;
        float4 v = *(const float4*)(W + (size_t)k * HID + c4 * 4);
        T[(c4 * 4 + 0) * HID + k] = bfr(v.x);
        T[(c4 * 4 + 1) * HID + k] = bfr(v.y);
        T[(c4 * 4 + 2) * HID + k] = bfr(v.z);
        T[(c4 * 4 + 3) * HID + k] = bfr(v.w);
    }
}

// ---------------------------------------------------------------------------
// SpMM (bf16 features): s[n] = 0.9*(sum_e nrm_e*h[src_e] + dinv^2*h[n]) + 0.1*h0[n]
// One wave per node; lane holds packed bf16 pair (cols 2l, 2l+1) = 4B/lane.
// Main loop unrolled x16 (16 gather chains in flight); masked x4 tail.
// ---------------------------------------------------------------------------
__global__ __launch_bounds__(256) void k_spmm(const uint* __restrict__ h,
                                              const uint* __restrict__ h0,
                                              const float* __restrict__ dinv,
                                              const int* __restrict__ indptr8,
                                              const int2* __restrict__ csr,
                                              uint* __restrict__ s_out) {
    int node = blockIdx.x * 4 + (threadIdx.x >> 6);
    if (node >= N_NODES) return;
    int lane = threadIdx.x & 63;
    int beg = indptr8[node * SH];
    int end = indptr8[node * SH + SH];
    // prefetch self/residual rows early (independent of edge loop)
    float di = dinv[node];
    uint hs = h[node * 64 + lane];
    uint h0v = h0[node * 64 + lane];
    float ax[8], ay[8];
#pragma unroll
    for (int j = 0; j < 8; ++j) { ax[j] = 0.f; ay[j] = 0.f; }
    int e = beg;
    for (; e + 16 <= end; e += 16) {
        int2 rr[16];
#pragma unroll
        for (int j = 0; j < 16; ++j) rr[j] = csr[e + j];
        uint p[16];
#pragma unroll
        for (int j = 0; j < 16; ++j) p[j] = h[rr[j].x * 64 + lane];
#pragma unroll
        for (int j = 0; j < 16; ++j) {
            float w = __int_as_float(rr[j].y);
            ax[j & 7] = fmaf(w, bf_lo(p[j]), ax[j & 7]);
            ay[j & 7] = fmaf(w, bf_hi(p[j]), ay[j & 7]);
        }
    }
    for (; e < end; e += 4) {
        int2 rr[4];
        float w[4];
#pragma unroll
        for (int j = 0; j < 4; ++j) {
            int idx = e + j;
            rr[j] = csr[idx < end ? idx : beg];
            w[j] = (idx < end) ? __int_as_float(rr[j].y) : 0.f;
        }
        uint p[4];
#pragma unroll
        for (int j = 0; j < 4; ++j) p[j] = h[rr[j].x * 64 + lane];
#pragma unroll
        for (int j = 0; j < 4; ++j) {
            ax[j] = fmaf(w[j], bf_lo(p[j]), ax[j]);
            ay[j] = fmaf(w[j], bf_hi(p[j]), ay[j]);
        }
    }
    float sum0 = ((ax[0] + ax[1]) + (ax[2] + ax[3])) + ((ax[4] + ax[5]) + (ax[6] + ax[7]));
    float sum1 = ((ay[0] + ay[1]) + (ay[2] + ay[3])) + ((ay[4] + ay[5]) + (ay[6] + ay[7]));
    float selfw = di * di;
    float rx = (1.0f - ALPHA) * fmaf(selfw, bf_lo(hs), sum0) + ALPHA * bf_lo(h0v);
    float ry = (1.0f - ALPHA) * fmaf(selfw, bf_hi(hs), sum1) + ALPHA * bf_hi(h0v);
    s_out[node * 64 + lane] = bf_pack(rx, ry);
}

// ---------------------------------------------------------------------------
// GEMM initial projection: out0 = out1 = x@W_in + b_in  (fp32 in, bf16 out x2)
// VALU path (runs once). 64 rows/block, K chunked by 32, 4x8 micro-tile.
// ---------------------------------------------------------------------------
__global__ __launch_bounds__(256) void k_gemm_in(const float* __restrict__ A,
                                                 const float* __restrict__ W,
                                                 const float* __restrict__ bias,
                                                 uint* __restrict__ out0,
                                                 uint* __restrict__ out1) {
    __shared__ float sT[32 * 64];    // [k][r]
    __shared__ float Ws[32 * 128];   // [k][c]
    int t = threadIdx.x;
    int tr = t & 15;
    int tc = t >> 4;
    int rowBase = blockIdx.x * 64;
    float acc[4][8] = {};

    for (int ko = 0; ko < HID; ko += 32) {
#pragma unroll
        for (int pass = 0; pass < 2; ++pass) {
            int lin = t + 256 * pass;
            int r = lin >> 3;
            int kq = lin & 7;
            int ar = rowBase + r;
            if (ar >= N_NODES) ar = N_NODES - 1;
            float4 v = *(const float4*)(A + (size_t)ar * HID + ko + 4 * kq);
            sT[(4 * kq + 0) * 64 + r] = v.x;
            sT[(4 * kq + 1) * 64 + r] = v.y;
            sT[(4 * kq + 2) * 64 + r] = v.z;
            sT[(4 * kq + 3) * 64 + r] = v.w;
        }
#pragma unroll
        for (int pass = 0; pass < 4; ++pass) {
            int lin = t + 256 * pass;
            int k = lin >> 5;
            int c4 = lin & 31;
            *(float4*)&Ws[k * 128 + 4 * c4] =
                *(const float4*)(W + (size_t)(ko + k) * HID + 4 * c4);
        }
        __syncthreads();
#pragma unroll
        for (int k = 0; k < 32; ++k) {
            float4 a = *(const float4*)&sT[k * 64 + 4 * tr];
            float4 w0 = *(const float4*)&Ws[k * 128 + 8 * tc];
            float4 w1 = *(const float4*)&Ws[k * 128 + 8 * tc + 4];
            float av[4] = {a.x, a.y, a.z, a.w};
            float wv[8] = {w0.x, w0.y, w0.z, w0.w, w1.x, w1.y, w1.z, w1.w};
#pragma unroll
            for (int i = 0; i < 4; ++i)
#pragma unroll
                for (int j = 0; j < 8; ++j)
                    acc[i][j] = fmaf(av[i], wv[j], acc[i][j]);
        }
        __syncthreads();
    }

    int c0 = 8 * tc;
    float bb[8];
#pragma unroll
    for (int j = 0; j < 8; ++j) bb[j] = bias[c0 + j];
#pragma unroll
    for (int i = 0; i < 4; ++i) {
        int r = rowBase + 4 * tr + i;
        if (r >= N_NODES) break;
        float v[8];
#pragma unroll
        for (int j = 0; j < 8; ++j) v[j] = acc[i][j] + bb[j];
        uint4 o;
        o.x = bf_pack(v[0], v[1]);
        o.y = bf_pack(v[2], v[3]);
        o.z = bf_pack(v[4], v[5]);
        o.w = bf_pack(v[6], v[7]);
        *(uint4*)(out0 + (size_t)r * 64 + c0 / 2) = o;
        *(uint4*)(out1 + (size_t)r * 64 + c0 / 2) = o;
    }
}

// ---------------------------------------------------------------------------
// GCNII layer GEMM (MFMA bf16): out = relu((1-beta)*s + beta*(s@W))
// 64 rows x 128 cols per block, 4 waves; wave w owns cols [32w, 32w+32).
// ---------------------------------------------------------------------------
#define SAS 136   // ushort stride (128+8): 272B rows, 16B-aligned, bank-even

__global__ __launch_bounds__(256) void k_gemm_layer(const uint* __restrict__ A,
                                                    const ushort* __restrict__ Wt,
                                                    uint* __restrict__ out0,
                                                    float beta) {
    __shared__ ushort sA[64 * SAS];
    __shared__ ushort sW[128 * SAS];   // reused as pack[64][128] in epilogue
    int t = threadIdx.x;
    int lane = t & 63;
    int wv = t >> 6;
    int rowBase = blockIdx.x * 64;

#pragma unroll
    for (int i = 0; i < 4; ++i) {
        int idx = t + 256 * i;          // 0..1023
        int r = idx >> 4;               // 0..63
        int q = idx & 15;               // uint4 within row
        int ar = rowBase + r;
        if (ar >= N_NODES) ar = N_NODES - 1;
        uint4 v = *(const uint4*)(A + (size_t)ar * 64 + q * 4);
        *(uint4*)((uint*)(sA + r * SAS) + q * 4) = v;
    }
#pragma unroll
    for (int i = 0; i < 8; ++i) {
        int idx = t + 256 * i;          // 0..2047
        int r = idx >> 4;               // 0..127
        int q = idx & 15;
        uint4 v = *(const uint4*)((const uint*)(Wt + (size_t)r * HID) + q * 4);
        *(uint4*)((uint*)(sW + r * SAS) + q * 4) = v;
    }
    __syncthreads();

    int fr = lane & 15;
    int fq = lane >> 4;
    f32x4 acc[4][2] = {};
#pragma unroll
    for (int kc = 0; kc < 4; ++kc) {
        int kof = kc * 32 + fq * 8;
        short8 b0 = *(const short8*)(sW + (wv * 32 + fr) * SAS + kof);
        short8 b1 = *(const short8*)(sW + (wv * 32 + 16 + fr) * SAS + kof);
#pragma unroll
        for (int tm = 0; tm < 4; ++tm) {
            short8 a = *(const short8*)(sA + (tm * 16 + fr) * SAS + kof);
            acc[tm][0] = __builtin_amdgcn_mfma_f32_16x16x32_bf16(a, b0, acc[tm][0], 0, 0, 0);
            acc[tm][1] = __builtin_amdgcn_mfma_f32_16x16x32_bf16(a, b1, acc[tm][1], 0, 0, 0);
        }
    }
    __syncthreads();   // all waves done reading sW; reuse it as pack buffer

    ushort* pack = sW; // [64][128] tight
    float ob = 1.0f - beta;
#pragma unroll
    for (int tm = 0; tm < 4; ++tm)
#pragma unroll
        for (int tn = 0; tn < 2; ++tn)
#pragma unroll
            for (int r = 0; r < 4; ++r) {
                int row = tm * 16 + fq * 4 + r;
                int col = wv * 32 + tn * 16 + fr;
                float sv = bff(sA[row * SAS + col]);
                float val = fmaxf(fmaf(ob, sv, beta * acc[tm][tn][r]), 0.f);
                pack[row * 128 + col] = bfr(val);
            }
    __syncthreads();
#pragma unroll
    for (int i = 0; i < 4; ++i) {
        int idx = t + 256 * i;
        int r = idx >> 4;
        int q = idx & 15;
        int ar = rowBase + r;
        if (ar < N_NODES)
            *(uint4*)(out0 + (size_t)ar * 64 + q * 4) =
                *(const uint4*)((const uint*)(pack + r * 128) + q * 4);
    }
}

// ---------------------------------------------------------------------------
// Output: out[n] = dot(h[n], W_out) + b_out   (wave per node, bf16 h)
// ---------------------------------------------------------------------------
__global__ __launch_bounds__(256) void k_out(const uint* __restrict__ h,
                                             const float* __restrict__ W_out,
                                             const float* __restrict__ b_out,
                                             float* __restrict__ out) {
    int node = blockIdx.x * 4 + (threadIdx.x >> 6);
    if (node >= N_NODES) return;
    int lane = threadIdx.x & 63;
    uint p = h[node * 64 + lane];
    float2 wv = *(const float2*)(W_out + lane * 2);
    float pr = bf_lo(p) * wv.x + bf_hi(p) * wv.y;
#pragma unroll
    for (int off = 32; off > 0; off >>= 1) pr += __shfl_down(pr, off);
    if (lane == 0) out[node] = pr + b_out[0];
}

// ---------------------------------------------------------------------------
extern "C" void kernel_launch(void* const* d_in, const int* in_sizes, int n_in,
                              void* d_out, int out_size, void* d_ws, size_t ws_size,
                              hipStream_t stream) {
    const float* x     = (const float*)d_in[0];
    // d_in[1] edge_weight: unused by reference forward path
    const float* W_in  = (const float*)d_in[2];
    const float* b_in  = (const float*)d_in[3];
    const float* W_gcn = (const float*)d_in[4];
    const float* W_out = (const float*)d_in[5];
    const float* b_out = (const float*)d_in[6];
    const int*   ei    = (const int*)d_in[7];
    const int* rowi = ei;
    const int* coli = ei + N_EDGES;
    float* out = (float*)d_out;

    char* ws = (char*)d_ws;
    auto alloc = [&](size_t bytes) -> char* {
        char* p = ws;
        ws += (bytes + 255) & ~(size_t)255;
        return p;
    };
    int*    cnt8    = (int*)   alloc((size_t)NODES8 * 4);
    float*  dinv    = (float*) alloc((size_t)N_NODES * 4);
    int*    indptr8 = (int*)   alloc((size_t)(NODES8 + 8) * 4);
    int*    bktcnt8 = (int*)   alloc((size_t)NBKT8 * 4);
    int*    bktcur  = (int*)   alloc((size_t)NBKT8 * 4);
    int*    bktptr8 = (int*)   alloc((size_t)(NBKT8 + 8) * 4);
    int*    bsum    = (int*)   alloc(1024 * 4);
    int*    boff    = (int*)   alloc(1024 * 4);
    int2*   binned  = (int2*)  alloc((size_t)N_EDGES * 8);
    int2*   csr     = (int2*)  alloc((size_t)N_EDGES * 8);
    ushort* Wt      = (ushort*)alloc((size_t)LAYERS * HID * HID * 2);
    uint*   hA      = (uint*)  alloc((size_t)N_NODES * 64 * 4);  // bf16 x2 packed
    uint*   hB      = (uint*)  alloc((size_t)N_NODES * 64 * 4);
    uint*   h0      = (uint*)  alloc((size_t)N_NODES * 64 * 4);

    hipMemsetAsync(cnt8, 0, (size_t)NODES8 * 4, stream);
    hipMemsetAsync(bktcnt8, 0, (size_t)NBKT8 * 4, stream);

    k_count<<<(N_EDGES + 255) / 256, 256, 0, stream>>>(rowi, coli, cnt8, bktcnt8);
    k_dinv<<<(N_NODES + 255) / 256, 256, 0, stream>>>(cnt8, dinv);
    k_scan1<<<NB_SCAN, 256, 0, stream>>>(cnt8, indptr8, bsum);
    k_scan2<<<1, 256, 0, stream>>>(bsum, boff);
    k_scan3<<<NB_SCAN, 256, 0, stream>>>(indptr8, boff);
    k_bscan<<<1, 256, 0, stream>>>(bktcnt8, bktcur, bktptr8);
    k_bin<<<(N_EDGES + 255) / 256, 256, 0, stream>>>(rowi, coli, dinv, bktcur, binned);
    k_scatter<<<NBKT, 256, 0, stream>>>(binned, bktptr8, indptr8, csr);
    k_wprep<<<LAYERS, 256, 0, stream>>>(W_gcn, Wt);

    int gemm_blocks = (N_NODES + 63) / 64;
    // h0 = hA = x@W_in + b_in
    k_gemm_in<<<gemm_blocks, 256, 0, stream>>>(x, W_in, b_in, h0, hA);

    for (int l = 0; l < LAYERS; ++l) {
        k_spmm<<<(N_NODES + 3) / 4, 256, 0, stream>>>(hA, h0, dinv, indptr8,
                                                      csr, hB);
        float beta = logf(THETA / (float)(l + 1) + 1.0f);
        k_gemm_layer<<<gemm_blocks, 256, 0, stream>>>(
            hB, Wt + (size_t)l * HID * HID, hA, beta);
    }
    k_out<<<(N_NODES + 3) / 4, 256, 0, stream>>>(hA, W_out, b_out, out);
}

// Round 6
// 1517.211 us; speedup vs baseline: 1.1867x; 1.1867x over previous
//
#include <hip/hip_runtime.h>
#include <hip/hip_bf16.h>
#include <math.h>

// Problem constants (match reference)
#define N_NODES 100000
#define N_EDGES 3200000
#define HID 128
#define LAYERS 8
#define ALPHA 0.1f
#define THETA 0.5f

#define SCAN_TILE 1024                       // elems per scan block (256 thr x 4)
#define NB_SCAN ((N_NODES + SCAN_TILE - 1) / SCAN_TILE)   // 98

typedef unsigned int uint;
typedef unsigned short ushort;
typedef __attribute__((ext_vector_type(8))) short short8;   // 8 bf16 (4 VGPRs)
typedef __attribute__((ext_vector_type(4))) float f32x4;    // MFMA acc

// bf16 helpers: node features stored as packed bf16 pairs (uint = 2 cols)
__device__ inline float bf_lo(uint p) { return __uint_as_float(p << 16); }
__device__ inline float bf_hi(uint p) { return __uint_as_float(p & 0xffff0000u); }
__device__ inline uint bf_pack(float x, float y) {
    uint ux = __float_as_uint(x), uy = __float_as_uint(y);
    uint rx = (ux + 0x7fffu + ((ux >> 16) & 1u)) >> 16;
    uint ry = (uy + 0x7fffu + ((uy >> 16) & 1u)) >> 16;
    return rx | (ry << 16);
}
__device__ inline ushort bfr(float x) {
    uint u = __float_as_uint(x);
    return (ushort)((u + 0x7fffu + ((u >> 16) & 1u)) >> 16);
}
__device__ inline float bff(ushort s) { return __uint_as_float(((uint)s) << 16); }

// ---------------------------------------------------------------------------
// CSR build — simple 100k-entry histogram (L2-resident, cheap atomics).
// Round-5 lesson: widening the atomic table to 800k+ entries makes every
// atomic an L2-missing RMW (~64B HBM-side traffic per edge). Keep it small.
// ---------------------------------------------------------------------------
__global__ __launch_bounds__(256) void k_count(const int* __restrict__ col,
                                               int* __restrict__ cnt) {
    int e = blockIdx.x * 256 + threadIdx.x;
    if (e < N_EDGES) atomicAdd(&cnt[col[e]], 1);
}

__global__ __launch_bounds__(256) void k_dinv(const int* __restrict__ cnt,
                                              float* __restrict__ dinv) {
    int n = blockIdx.x * 256 + threadIdx.x;
    if (n < N_NODES) dinv[n] = rsqrtf((float)(cnt[n] + 1));  // +1 self loop
}

__global__ __launch_bounds__(256) void k_scan1(const int* __restrict__ cnt,
                                               int* __restrict__ indptr,
                                               int* __restrict__ bsum) {
    __shared__ int lds[256];
    int t = threadIdx.x;
    int base = blockIdx.x * SCAN_TILE + t * 4;
    int v[4];
    int s = 0;
#pragma unroll
    for (int j = 0; j < 4; ++j) {
        v[j] = (base + j < N_NODES) ? cnt[base + j] : 0;
        s += v[j];
    }
    lds[t] = s;
    __syncthreads();
    for (int off = 1; off < 256; off <<= 1) {
        int u = (t >= off) ? lds[t - off] : 0;
        __syncthreads();
        lds[t] += u;
        __syncthreads();
    }
    int run = lds[t] - s;
#pragma unroll
    for (int j = 0; j < 4; ++j) {
        if (base + j < N_NODES) indptr[base + j] = run;
        run += v[j];
    }
    if (t == 255) bsum[blockIdx.x] = lds[255];
}

__global__ __launch_bounds__(256) void k_scan2(const int* __restrict__ bsum,
                                               int* __restrict__ boff) {
    __shared__ int lds[256];
    int t = threadIdx.x;
    int v = (t < NB_SCAN) ? bsum[t] : 0;
    lds[t] = v;
    __syncthreads();
    for (int off = 1; off < 256; off <<= 1) {
        int u = (t >= off) ? lds[t - off] : 0;
        __syncthreads();
        lds[t] += u;
        __syncthreads();
    }
    boff[t] = lds[t] - v;
}

__global__ __launch_bounds__(256) void k_scan3(int* __restrict__ indptr,
                                               const int* __restrict__ boff) {
    int base = blockIdx.x * SCAN_TILE + threadIdx.x * 4;
    int add = boff[blockIdx.x];
#pragma unroll
    for (int j = 0; j < 4; ++j) {
        if (base + j < N_NODES) indptr[base + j] += add;
    }
    if (blockIdx.x == 0 && threadIdx.x == 0) indptr[N_NODES] = N_EDGES;
}

// Interleaved CSR record: one 8B store per edge (one cacheline touch)
__global__ __launch_bounds__(256) void k_fill(const int* __restrict__ rowi,
                                              const int* __restrict__ coli,
                                              const float* __restrict__ dinv,
                                              const int* __restrict__ indptr,
                                              int* __restrict__ cursor,
                                              int2* __restrict__ csr) {
    int e = blockIdx.x * 256 + threadIdx.x;
    if (e >= N_EDGES) return;
    int r = rowi[e];
    int c = coli[e];
    int p = indptr[c] + atomicAdd(&cursor[c], 1);
    csr[p] = make_int2(r, __float_as_int(dinv[r] * dinv[c]));
}

// ---------------------------------------------------------------------------
// W_gcn prep: bf16 + transpose -> Wt[l][c][k]  (runs once per call, 8 blocks)
// ---------------------------------------------------------------------------
__global__ __launch_bounds__(256) void k_wprep(const float* __restrict__ Wg,
                                               ushort* __restrict__ Wt) {
    int l = blockIdx.x;
    const float* W = Wg + (size_t)l * HID * HID;
    ushort* T = Wt + (size_t)l * HID * HID;
    int t = threadIdx.x;
#pragma unroll
    for (int i = 0; i < 16; ++i) {
        int idx = t + 256 * i;          // float4 id, 0..4095
        int k = idx >> 5;               // 0..127
        int c4 = idx & 31;
        float4 v = *(const float4*)(W + (size_t)k * HID + c4 * 4);
        T[(c4 * 4 + 0) * HID + k] = bfr(v.x);
        T[(c4 * 4 + 1) * HID + k] = bfr(v.y);
        T[(c4 * 4 + 2) * HID + k] = bfr(v.z);
        T[(c4 * 4 + 3) * HID + k] = bfr(v.w);
    }
}

// ---------------------------------------------------------------------------
// SpMM (bf16 features): s[n] = 0.9*(sum_e nrm_e*h[src_e] + dinv^2*h[n]) + 0.1*h0[n]
// One wave per node; lane holds packed bf16 pair (cols 2l, 2l+1) = 4B/lane.
// Main loop unrolled x16 (16 gather chains in flight); masked x4 tail.
// ---------------------------------------------------------------------------
__global__ __launch_bounds__(256) void k_spmm(const uint* __restrict__ h,
                                              const uint* __restrict__ h0,
                                              const float* __restrict__ dinv,
                                              const int* __restrict__ indptr,
                                              const int2* __restrict__ csr,
                                              uint* __restrict__ s_out) {
    int node = blockIdx.x * 4 + (threadIdx.x >> 6);
    if (node >= N_NODES) return;
    int lane = threadIdx.x & 63;
    int beg = indptr[node];
    int end = indptr[node + 1];
    // prefetch self/residual rows early (independent of edge loop)
    float di = dinv[node];
    uint hs = h[node * 64 + lane];
    uint h0v = h0[node * 64 + lane];
    float ax[8], ay[8];
#pragma unroll
    for (int j = 0; j < 8; ++j) { ax[j] = 0.f; ay[j] = 0.f; }
    int e = beg;
    for (; e + 16 <= end; e += 16) {
        int2 rr[16];
#pragma unroll
        for (int j = 0; j < 16; ++j) rr[j] = csr[e + j];
        uint p[16];
#pragma unroll
        for (int j = 0; j < 16; ++j) p[j] = h[rr[j].x * 64 + lane];
#pragma unroll
        for (int j = 0; j < 16; ++j) {
            float w = __int_as_float(rr[j].y);
            ax[j & 7] = fmaf(w, bf_lo(p[j]), ax[j & 7]);
            ay[j & 7] = fmaf(w, bf_hi(p[j]), ay[j & 7]);
        }
    }
    for (; e < end; e += 4) {
        int2 rr[4];
        float w[4];
#pragma unroll
        for (int j = 0; j < 4; ++j) {
            int idx = e + j;
            rr[j] = csr[idx < end ? idx : beg];
            w[j] = (idx < end) ? __int_as_float(rr[j].y) : 0.f;
        }
        uint p[4];
#pragma unroll
        for (int j = 0; j < 4; ++j) p[j] = h[rr[j].x * 64 + lane];
#pragma unroll
        for (int j = 0; j < 4; ++j) {
            ax[j] = fmaf(w[j], bf_lo(p[j]), ax[j]);
            ay[j] = fmaf(w[j], bf_hi(p[j]), ay[j]);
        }
    }
    float sum0 = ((ax[0] + ax[1]) + (ax[2] + ax[3])) + ((ax[4] + ax[5]) + (ax[6] + ax[7]));
    float sum1 = ((ay[0] + ay[1]) + (ay[2] + ay[3])) + ((ay[4] + ay[5]) + (ay[6] + ay[7]));
    float selfw = di * di;
    float rx = (1.0f - ALPHA) * fmaf(selfw, bf_lo(hs), sum0) + ALPHA * bf_lo(h0v);
    float ry = (1.0f - ALPHA) * fmaf(selfw, bf_hi(hs), sum1) + ALPHA * bf_hi(h0v);
    s_out[node * 64 + lane] = bf_pack(rx, ry);
}

// ---------------------------------------------------------------------------
// GEMM initial projection: out0 = out1 = x@W_in + b_in  (fp32 in, bf16 out x2)
// VALU path (runs once). 64 rows/block, K chunked by 32, 4x8 micro-tile.
// ---------------------------------------------------------------------------
__global__ __launch_bounds__(256) void k_gemm_in(const float* __restrict__ A,
                                                 const float* __restrict__ W,
                                                 const float* __restrict__ bias,
                                                 uint* __restrict__ out0,
                                                 uint* __restrict__ out1) {
    __shared__ float sT[32 * 64];    // [k][r]
    __shared__ float Ws[32 * 128];   // [k][c]
    int t = threadIdx.x;
    int tr = t & 15;
    int tc = t >> 4;
    int rowBase = blockIdx.x * 64;
    float acc[4][8] = {};

    for (int ko = 0; ko < HID; ko += 32) {
#pragma unroll
        for (int pass = 0; pass < 2; ++pass) {
            int lin = t + 256 * pass;
            int r = lin >> 3;
            int kq = lin & 7;
            int ar = rowBase + r;
            if (ar >= N_NODES) ar = N_NODES - 1;
            float4 v = *(const float4*)(A + (size_t)ar * HID + ko + 4 * kq);
            sT[(4 * kq + 0) * 64 + r] = v.x;
            sT[(4 * kq + 1) * 64 + r] = v.y;
            sT[(4 * kq + 2) * 64 + r] = v.z;
            sT[(4 * kq + 3) * 64 + r] = v.w;
        }
#pragma unroll
        for (int pass = 0; pass < 4; ++pass) {
            int lin = t + 256 * pass;
            int k = lin >> 5;
            int c4 = lin & 31;
            *(float4*)&Ws[k * 128 + 4 * c4] =
                *(const float4*)(W + (size_t)(ko + k) * HID + 4 * c4);
        }
        __syncthreads();
#pragma unroll
        for (int k = 0; k < 32; ++k) {
            float4 a = *(const float4*)&sT[k * 64 + 4 * tr];
            float4 w0 = *(const float4*)&Ws[k * 128 + 8 * tc];
            float4 w1 = *(const float4*)&Ws[k * 128 + 8 * tc + 4];
            float av[4] = {a.x, a.y, a.z, a.w};
            float wv[8] = {w0.x, w0.y, w0.z, w0.w, w1.x, w1.y, w1.z, w1.w};
#pragma unroll
            for (int i = 0; i < 4; ++i)
#pragma unroll
                for (int j = 0; j < 8; ++j)
                    acc[i][j] = fmaf(av[i], wv[j], acc[i][j]);
        }
        __syncthreads();
    }

    int c0 = 8 * tc;
    float bb[8];
#pragma unroll
    for (int j = 0; j < 8; ++j) bb[j] = bias[c0 + j];
#pragma unroll
    for (int i = 0; i < 4; ++i) {
        int r = rowBase + 4 * tr + i;
        if (r >= N_NODES) break;
        float v[8];
#pragma unroll
        for (int j = 0; j < 8; ++j) v[j] = acc[i][j] + bb[j];
        uint4 o;
        o.x = bf_pack(v[0], v[1]);
        o.y = bf_pack(v[2], v[3]);
        o.z = bf_pack(v[4], v[5]);
        o.w = bf_pack(v[6], v[7]);
        *(uint4*)(out0 + (size_t)r * 64 + c0 / 2) = o;
        *(uint4*)(out1 + (size_t)r * 64 + c0 / 2) = o;
    }
}

// ---------------------------------------------------------------------------
// GCNII layer GEMM (MFMA bf16): out = relu((1-beta)*s + beta*(s@W))
// 64 rows x 128 cols per block, 4 waves; wave w owns cols [32w, 32w+32).
// ---------------------------------------------------------------------------
#define SAS 136   // ushort stride (128+8): 272B rows, 16B-aligned, bank-even

__global__ __launch_bounds__(256) void k_gemm_layer(const uint* __restrict__ A,
                                                    const ushort* __restrict__ Wt,
                                                    uint* __restrict__ out0,
                                                    float beta) {
    __shared__ ushort sA[64 * SAS];
    __shared__ ushort sW[128 * SAS];   // reused as pack[64][128] in epilogue
    int t = threadIdx.x;
    int lane = t & 63;
    int wv = t >> 6;
    int rowBase = blockIdx.x * 64;

#pragma unroll
    for (int i = 0; i < 4; ++i) {
        int idx = t + 256 * i;          // 0..1023
        int r = idx >> 4;               // 0..63
        int q = idx & 15;               // uint4 within row
        int ar = rowBase + r;
        if (ar >= N_NODES) ar = N_NODES - 1;
        uint4 v = *(const uint4*)(A + (size_t)ar * 64 + q * 4);
        *(uint4*)((uint*)(sA + r * SAS) + q * 4) = v;
    }
#pragma unroll
    for (int i = 0; i < 8; ++i) {
        int idx = t + 256 * i;          // 0..2047
        int r = idx >> 4;               // 0..127
        int q = idx & 15;
        uint4 v = *(const uint4*)((const uint*)(Wt + (size_t)r * HID) + q * 4);
        *(uint4*)((uint*)(sW + r * SAS) + q * 4) = v;
    }
    __syncthreads();

    int fr = lane & 15;
    int fq = lane >> 4;
    f32x4 acc[4][2] = {};
#pragma unroll
    for (int kc = 0; kc < 4; ++kc) {
        int kof = kc * 32 + fq * 8;
        short8 b0 = *(const short8*)(sW + (wv * 32 + fr) * SAS + kof);
        short8 b1 = *(const short8*)(sW + (wv * 32 + 16 + fr) * SAS + kof);
#pragma unroll
        for (int tm = 0; tm < 4; ++tm) {
            short8 a = *(const short8*)(sA + (tm * 16 + fr) * SAS + kof);
            acc[tm][0] = __builtin_amdgcn_mfma_f32_16x16x32_bf16(a, b0, acc[tm][0], 0, 0, 0);
            acc[tm][1] = __builtin_amdgcn_mfma_f32_16x16x32_bf16(a, b1, acc[tm][1], 0, 0, 0);
        }
    }
    __syncthreads();   // all waves done reading sW; reuse it as pack buffer

    ushort* pack = sW; // [64][128] tight
    float ob = 1.0f - beta;
#pragma unroll
    for (int tm = 0; tm < 4; ++tm)
#pragma unroll
        for (int tn = 0; tn < 2; ++tn)
#pragma unroll
            for (int r = 0; r < 4; ++r) {
                int row = tm * 16 + fq * 4 + r;
                int col = wv * 32 + tn * 16 + fr;
                float sv = bff(sA[row * SAS + col]);
                float val = fmaxf(fmaf(ob, sv, beta * acc[tm][tn][r]), 0.f);
                pack[row * 128 + col] = bfr(val);
            }
    __syncthreads();
#pragma unroll
    for (int i = 0; i < 4; ++i) {
        int idx = t + 256 * i;
        int r = idx >> 4;
        int q = idx & 15;
        int ar = rowBase + r;
        if (ar < N_NODES)
            *(uint4*)(out0 + (size_t)ar * 64 + q * 4) =
                *(const uint4*)((const uint*)(pack + r * 128) + q * 4);
    }
}

// ---------------------------------------------------------------------------
// Output: out[n] = dot(h[n], W_out) + b_out   (wave per node, bf16 h)
// ---------------------------------------------------------------------------
__global__ __launch_bounds__(256) void k_out(const uint* __restrict__ h,
                                             const float* __restrict__ W_out,
                                             const float* __restrict__ b_out,
                                             float* __restrict__ out) {
    int node = blockIdx.x * 4 + (threadIdx.x >> 6);
    if (node >= N_NODES) return;
    int lane = threadIdx.x & 63;
    uint p = h[node * 64 + lane];
    float2 wv = *(const float2*)(W_out + lane * 2);
    float pr = bf_lo(p) * wv.x + bf_hi(p) * wv.y;
#pragma unroll
    for (int off = 32; off > 0; off >>= 1) pr += __shfl_down(pr, off);
    if (lane == 0) out[node] = pr + b_out[0];
}

// ---------------------------------------------------------------------------
extern "C" void kernel_launch(void* const* d_in, const int* in_sizes, int n_in,
                              void* d_out, int out_size, void* d_ws, size_t ws_size,
                              hipStream_t stream) {
    const float* x     = (const float*)d_in[0];
    // d_in[1] edge_weight: unused by reference forward path
    const float* W_in  = (const float*)d_in[2];
    const float* b_in  = (const float*)d_in[3];
    const float* W_gcn = (const float*)d_in[4];
    const float* W_out = (const float*)d_in[5];
    const float* b_out = (const float*)d_in[6];
    const int*   ei    = (const int*)d_in[7];
    const int* rowi = ei;
    const int* coli = ei + N_EDGES;
    float* out = (float*)d_out;

    char* ws = (char*)d_ws;
    auto alloc = [&](size_t bytes) -> char* {
        char* p = ws;
        ws += (bytes + 255) & ~(size_t)255;
        return p;
    };
    int*    cnt     = (int*)   alloc((size_t)N_NODES * 4);
    float*  dinv    = (float*) alloc((size_t)N_NODES * 4);
    int*    indptr  = (int*)   alloc((size_t)(N_NODES + 1) * 4);
    int*    cursor  = (int*)   alloc((size_t)N_NODES * 4);
    int*    bsum    = (int*)   alloc(1024 * 4);
    int*    boff    = (int*)   alloc(1024 * 4);
    int2*   csr     = (int2*)  alloc((size_t)N_EDGES * 8);
    ushort* Wt      = (ushort*)alloc((size_t)LAYERS * HID * HID * 2);
    uint*   hA      = (uint*)  alloc((size_t)N_NODES * 64 * 4);  // bf16 x2 packed
    uint*   hB      = (uint*)  alloc((size_t)N_NODES * 64 * 4);
    uint*   h0      = (uint*)  alloc((size_t)N_NODES * 64 * 4);

    hipMemsetAsync(cnt, 0, (size_t)N_NODES * 4, stream);
    hipMemsetAsync(cursor, 0, (size_t)N_NODES * 4, stream);

    k_count<<<(N_EDGES + 255) / 256, 256, 0, stream>>>(coli, cnt);
    k_dinv<<<(N_NODES + 255) / 256, 256, 0, stream>>>(cnt, dinv);
    k_scan1<<<NB_SCAN, 256, 0, stream>>>(cnt, indptr, bsum);
    k_scan2<<<1, 256, 0, stream>>>(bsum, boff);
    k_scan3<<<NB_SCAN, 256, 0, stream>>>(indptr, boff);
    k_fill<<<(N_EDGES + 255) / 256, 256, 0, stream>>>(rowi, coli, dinv, indptr,
                                                      cursor, csr);
    k_wprep<<<LAYERS, 256, 0, stream>>>(W_gcn, Wt);

    int gemm_blocks = (N_NODES + 63) / 64;
    // h0 = hA = x@W_in + b_in
    k_gemm_in<<<gemm_blocks, 256, 0, stream>>>(x, W_in, b_in, h0, hA);

    for (int l = 0; l < LAYERS; ++l) {
        k_spmm<<<(N_NODES + 3) / 4, 256, 0, stream>>>(hA, h0, dinv, indptr,
                                                      csr, hB);
        float beta = logf(THETA / (float)(l + 1) + 1.0f);
        k_gemm_layer<<<gemm_blocks, 256, 0, stream>>>(
            hB, Wt + (size_t)l * HID * HID, hA, beta);
    }
    k_out<<<(N_NODES + 3) / 4, 256, 0, stream>>>(hA, W_out, b_out, out);
}